// Round 1
// baseline (700.324 us; speedup 1.0000x reference)
//
#include <hip/hip_runtime.h>
#include <hip/hip_bf16.h>
#include <math.h>

// MoD router: B=4, L=8192, D=2048, capacity=4096
// out layout (float32): mask[B*L] ++ logits[B*L] ++ aux_loss[1]
// ws layout: keys[B*L] (uint32, order-preserving map of noisy logits) ++ row_sums[B] (double)

#define BATCH 4
#define SEQ 8192
#define DIM 2048
#define CAP 4096

// ---------------- Kernel 1: per-token GEMV + noisy-key generation ----------------
// block = 256 (4 waves), each wave computes 4 tokens; grid = B*L/16 = 2048
__global__ __launch_bounds__(256) void gemv_kernel(
    const float* __restrict__ x, const float* __restrict__ noise,
    const float* __restrict__ w, float* __restrict__ logits_out,
    unsigned* __restrict__ keys_out)
{
    __shared__ float w_lds[DIM];
    const int tid = threadIdx.x;
    // stage w into LDS: 2048 floats, 256 threads * 2 float4 each
    for (int i = tid * 4; i < DIM; i += 256 * 4) {
        *(float4*)(w_lds + i) = *(const float4*)(w + i);
    }
    __syncthreads();

    const int wave = tid >> 6;
    const int lane = tid & 63;
    const int tok_base = blockIdx.x * 16 + wave * 4;

    for (int t = 0; t < 4; ++t) {
        const int tok = tok_base + t;
        const float* xp = x + (size_t)tok * DIM;
        double acc = 0.0;
        // 2048 floats = 8 iters of (64 lanes x float4), coalesced 1KiB/instr
        #pragma unroll
        for (int i = 0; i < DIM; i += 64 * 4) {
            float4 xv = *(const float4*)(xp + i + lane * 4);
            float4 wv = *(const float4*)(w_lds + i + lane * 4);
            acc += (double)xv.x * wv.x + (double)xv.y * wv.y
                 + (double)xv.z * wv.z + (double)xv.w * wv.w;
        }
        // wave-64 shuffle reduction (double)
        #pragma unroll
        for (int off = 32; off > 0; off >>= 1)
            acc += __shfl_down(acc, off, 64);
        if (lane == 0) {
            float logit = (float)acc;
            logits_out[tok] = logit;
            float noisy = logit + noise[tok] * 0.1f;
            unsigned u = __float_as_uint(noisy);
            // order-preserving map: larger float -> larger uint
            keys_out[tok] = (u & 0x80000000u) ? ~u : (u | 0x80000000u);
        }
    }
}

// ---------------- Kernel 2: per-row exact top-k threshold (radix select) + mask + sigmoid sum ----
// one block (256 threads) per batch row
__global__ __launch_bounds__(256) void select_kernel(
    const unsigned* __restrict__ keys, const float* __restrict__ logits,
    float* __restrict__ mask_out, double* __restrict__ row_sums)
{
    const int b = blockIdx.x;
    const int tid = threadIdx.x;
    __shared__ unsigned k_lds[SEQ];       // 32 KB
    __shared__ int hist[256];
    __shared__ unsigned s_prefix;
    __shared__ int s_kneed;
    __shared__ double red[256];

    const unsigned* kp = keys + b * SEQ;
    for (int i = tid; i < SEQ; i += 256) k_lds[i] = kp[i];
    if (tid == 0) { s_prefix = 0u; s_kneed = CAP; }
    __syncthreads();

    // 4-pass MSB-first radix select: find T = CAP-th largest key
    for (int s = 24; s >= 0; s -= 8) {
        hist[tid] = 0;
        __syncthreads();
        const unsigned prefix = s_prefix;
        for (int i = tid; i < SEQ; i += 256) {
            unsigned key = k_lds[i];
            // candidate iff bits [s+8,32) match prefix; s=24 -> all candidates
            if (((unsigned long long)(key ^ prefix) >> (s + 8)) == 0ull)
                atomicAdd(&hist[(key >> s) & 255], 1);
        }
        __syncthreads();
        if (tid == 0) {
            int kneed = s_kneed, cum = 0, bsel = 0;
            for (int bb = 255; bb >= 0; --bb) {
                int c = hist[bb];
                if (cum + c >= kneed) { bsel = bb; s_kneed = kneed - cum; break; }
                cum += c;
            }
            s_prefix = prefix | ((unsigned)bsel << s);
        }
        __syncthreads();
    }
    const unsigned T = s_prefix;
    const int kneed = s_kneed;   // how many of the ties (== T) to take, lowest index first

    // write mask (coalesced); ties broken by lowest index (matches lax.top_k / stable argsort)
    float* mp = mask_out + b * SEQ;
    for (int i = tid; i < SEQ; i += 256) {
        unsigned key = k_lds[i];
        bool sel;
        if (key > T) sel = true;
        else if (key == T) {
            int rank = 0;                       // ties are ~always a single element; O(n) scan is fine
            for (int j = 0; j < i; ++j) rank += (k_lds[j] == T);
            sel = (rank < kneed);
        } else sel = false;
        mp[i] = sel ? 1.0f : 0.0f;
    }

    // sigmoid sum over clean logits (for aux loss)
    const float* lp = logits + b * SEQ;
    double acc = 0.0;
    for (int i = tid; i < SEQ; i += 256) {
        float v = lp[i];
        acc += (double)(1.0f / (1.0f + expf(-v)));
    }
    red[tid] = acc;
    __syncthreads();
    for (int off = 128; off > 0; off >>= 1) {
        if (tid < off) red[tid] += red[tid + off];
        __syncthreads();
    }
    if (tid == 0) row_sums[b] = red[0];
}

// ---------------- Kernel 3: aux loss ----------------
__global__ void finalize_kernel(const double* __restrict__ row_sums,
                                float* __restrict__ aux_out)
{
    if (threadIdx.x == 0 && blockIdx.x == 0) {
        double a = 0.0;
        for (int b = 0; b < BATCH; ++b) {
            double m = row_sums[b] / (double)SEQ - 0.5;
            a += m * m;
        }
        aux_out[0] = (float)(0.01 * (a / (double)BATCH));
    }
}

extern "C" void kernel_launch(void* const* d_in, const int* in_sizes, int n_in,
                              void* d_out, int out_size, void* d_ws, size_t ws_size,
                              hipStream_t stream) {
    const float* x     = (const float*)d_in[0];   // [B, L, D]
    const float* noise = (const float*)d_in[1];   // [B, L]
    const float* w     = (const float*)d_in[2];   // [D]

    float* mask_out   = (float*)d_out;                   // [B*L]
    float* logits_out = (float*)d_out + BATCH * SEQ;     // [B*L]
    float* aux_out    = (float*)d_out + 2 * BATCH * SEQ; // [1]

    unsigned* keys  = (unsigned*)d_ws;                                  // B*L uint32
    double* row_sums = (double*)((char*)d_ws + (size_t)BATCH * SEQ * 4); // 8B-aligned

    gemv_kernel<<<(BATCH * SEQ) / 16, 256, 0, stream>>>(x, noise, w, logits_out, keys);
    select_kernel<<<BATCH, 256, 0, stream>>>(keys, logits_out, mask_out, row_sums);
    finalize_kernel<<<1, 64, 0, stream>>>(row_sums, aux_out);
}

// Round 2
// 485.819 us; speedup vs baseline: 1.4415x; 1.4415x over previous
//
#include <hip/hip_runtime.h>
#include <hip/hip_bf16.h>
#include <math.h>

// MoD router: B=4, L=8192, D=2048, capacity=4096
// out layout (float32): mask[B*L] ++ logits[B*L] ++ aux_loss[1]
// ws layout: keys[B*L] (uint32, order-preserving map of noisy logits) ++ row_sums[B] (double)

#define BATCH 4
#define SEQ 8192
#define DIM 2048
#define CAP 4096

// ---------------- Kernel 1: per-token GEMV + noisy-key generation ----------------
// block = 256 (4 waves), each wave computes 4 tokens; grid = B*L/16 = 2048
__global__ __launch_bounds__(256) void gemv_kernel(
    const float* __restrict__ x, const float* __restrict__ noise,
    const float* __restrict__ w, float* __restrict__ logits_out,
    unsigned* __restrict__ keys_out)
{
    __shared__ float w_lds[DIM];
    const int tid = threadIdx.x;
    for (int i = tid * 4; i < DIM; i += 256 * 4) {
        *(float4*)(w_lds + i) = *(const float4*)(w + i);
    }
    __syncthreads();

    const int wave = tid >> 6;
    const int lane = tid & 63;
    const int tok_base = blockIdx.x * 16 + wave * 4;

    for (int t = 0; t < 4; ++t) {
        const int tok = tok_base + t;
        const float* xp = x + (size_t)tok * DIM;
        double acc = 0.0;
        #pragma unroll
        for (int i = 0; i < DIM; i += 64 * 4) {
            float4 xv = *(const float4*)(xp + i + lane * 4);
            float4 wv = *(const float4*)(w_lds + i + lane * 4);
            acc += (double)xv.x * wv.x + (double)xv.y * wv.y
                 + (double)xv.z * wv.z + (double)xv.w * wv.w;
        }
        #pragma unroll
        for (int off = 32; off > 0; off >>= 1)
            acc += __shfl_down(acc, off, 64);
        if (lane == 0) {
            float logit = (float)acc;
            logits_out[tok] = logit;
            float noisy = logit + noise[tok] * 0.1f;
            unsigned u = __float_as_uint(noisy);
            // order-preserving map: larger float -> larger uint
            keys_out[tok] = (u & 0x80000000u) ? ~u : (u | 0x80000000u);
        }
    }
}

// ---------------- Kernel 2: register-resident bitwise binary-search select ----------------
// One block (256 threads) per batch row. Each thread holds 32 keys in VGPRs.
// 32-bit MSB->LSB refinement finds T = CAP-th largest key exactly; no atomics,
// no histograms, no serial scans.
__global__ __launch_bounds__(256) void select_kernel(
    const unsigned* __restrict__ keys, const float* __restrict__ logits,
    float* __restrict__ mask_out, double* __restrict__ row_sums)
{
    const int b = blockIdx.x;
    const int tid = threadIdx.x;
    const int wv = tid >> 6;
    __shared__ unsigned k_lds[SEQ];   // 32 KB copy for tie-rank scan + mask write
    __shared__ int wsum[2][4];
    __shared__ double red[256];

    // Load keys: registers (for counting) + LDS (for tie handling)
    unsigned kreg[32];
    const unsigned* kp = keys + b * SEQ;
    #pragma unroll
    for (int j = 0; j < 32; ++j) {
        unsigned v = kp[j * 256 + tid];   // coalesced
        kreg[j] = v;
        k_lds[j * 256 + tid] = v;
    }

    // Bitwise binary search: thr ends as the largest value v with count(keys >= v) >= CAP,
    // i.e. exactly the CAP-th largest key.
    unsigned thr = 0u;
    #pragma unroll 1
    for (int bit = 31; bit >= 0; --bit) {
        const unsigned cand = thr | (1u << bit);
        int c = 0;
        #pragma unroll
        for (int j = 0; j < 32; ++j) c += (kreg[j] >= cand) ? 1 : 0;
        #pragma unroll
        for (int off = 32; off > 0; off >>= 1) c += __shfl_xor(c, off, 64);
        if ((tid & 63) == 0) wsum[bit & 1][wv] = c;   // double-buffered -> 1 barrier/iter
        __syncthreads();
        const int tot = wsum[bit & 1][0] + wsum[bit & 1][1]
                      + wsum[bit & 1][2] + wsum[bit & 1][3];
        if (tot >= CAP) thr = cand;
    }

    // Count strictly-greater to know how many ties (== thr) to take (lowest index first).
    // Last loop iter used wsum[0]; all wsum[1] readers are past the bit-0 barrier, so
    // writing wsum[1] here is race-free.
    int cg = 0;
    #pragma unroll
    for (int j = 0; j < 32; ++j) cg += (kreg[j] > thr) ? 1 : 0;
    #pragma unroll
    for (int off = 32; off > 0; off >>= 1) cg += __shfl_xor(cg, off, 64);
    if ((tid & 63) == 0) wsum[1][wv] = cg;
    __syncthreads();
    const int n_gt = wsum[1][0] + wsum[1][1] + wsum[1][2] + wsum[1][3];
    const int kneed = CAP - n_gt;   // ties to select, lowest index first

    // Mask write (coalesced); ties broken by lowest index (matches lax.top_k / stable argsort)
    float* mp = mask_out + b * SEQ;
    #pragma unroll
    for (int j = 0; j < 32; ++j) {
        const int i = j * 256 + tid;
        const unsigned key = kreg[j];
        bool sel;
        if (key > thr) sel = true;
        else if (key == thr) {
            int rank = 0;   // ties are ~always a single element; O(i) LDS scan is fine
            for (int jj = 0; jj < i; ++jj) rank += (k_lds[jj] == thr);
            sel = (rank < kneed);
        } else sel = false;
        mp[i] = sel ? 1.0f : 0.0f;
    }

    // Sigmoid sum over clean logits (for aux loss)
    const float* lp = logits + b * SEQ;
    double acc = 0.0;
    for (int i = tid; i < SEQ; i += 256) {
        float v = lp[i];
        acc += (double)(1.0f / (1.0f + expf(-v)));
    }
    red[tid] = acc;
    __syncthreads();
    for (int off = 128; off > 0; off >>= 1) {
        if (tid < off) red[tid] += red[tid + off];
        __syncthreads();
    }
    if (tid == 0) row_sums[b] = red[0];
}

// ---------------- Kernel 3: aux loss ----------------
__global__ void finalize_kernel(const double* __restrict__ row_sums,
                                float* __restrict__ aux_out)
{
    if (threadIdx.x == 0 && blockIdx.x == 0) {
        double a = 0.0;
        for (int b = 0; b < BATCH; ++b) {
            double m = row_sums[b] / (double)SEQ - 0.5;
            a += m * m;
        }
        aux_out[0] = (float)(0.01 * (a / (double)BATCH));
    }
}

extern "C" void kernel_launch(void* const* d_in, const int* in_sizes, int n_in,
                              void* d_out, int out_size, void* d_ws, size_t ws_size,
                              hipStream_t stream) {
    const float* x     = (const float*)d_in[0];   // [B, L, D]
    const float* noise = (const float*)d_in[1];   // [B, L]
    const float* w     = (const float*)d_in[2];   // [D]

    float* mask_out   = (float*)d_out;                   // [B*L]
    float* logits_out = (float*)d_out + BATCH * SEQ;     // [B*L]
    float* aux_out    = (float*)d_out + 2 * BATCH * SEQ; // [1]

    unsigned* keys   = (unsigned*)d_ws;                                   // B*L uint32
    double* row_sums = (double*)((char*)d_ws + (size_t)BATCH * SEQ * 4);  // 8B-aligned

    gemv_kernel<<<(BATCH * SEQ) / 16, 256, 0, stream>>>(x, noise, w, logits_out, keys);
    select_kernel<<<BATCH, 256, 0, stream>>>(keys, logits_out, mask_out, row_sums);
    finalize_kernel<<<1, 64, 0, stream>>>(row_sums, aux_out);
}

// Round 3
// 380.113 us; speedup vs baseline: 1.8424x; 1.2781x over previous
//
#include <hip/hip_runtime.h>
#include <hip/hip_bf16.h>
#include <math.h>

// MoD router: B=4, L=8192, D=2048, capacity=4096
// out layout (float32): mask[B*L] ++ logits[B*L] ++ aux_loss[1]
// ws layout: keys[B*L] uint32 (128 KB) ++ block_sums[2048] double (16 KB)

#define BATCH 4
#define SEQ 8192
#define DIM 2048
#define CAP 4096
#define GEMV_BLOCKS ((BATCH * SEQ) / 16)   // 2048, 512 per row

// ---------------- Kernel 1: per-token GEMV + noisy keys + fused sigmoid partials ----
// block = 256 (4 waves), each wave computes 4 tokens; grid = 2048
__global__ __launch_bounds__(256) void gemv_kernel(
    const float* __restrict__ x, const float* __restrict__ noise,
    const float* __restrict__ w, float* __restrict__ logits_out,
    unsigned* __restrict__ keys_out, double* __restrict__ block_sums)
{
    __shared__ float w_lds[DIM];
    __shared__ double ssum[4];
    const int tid = threadIdx.x;
    for (int i = tid * 4; i < DIM; i += 256 * 4) {
        *(float4*)(w_lds + i) = *(const float4*)(w + i);
    }
    __syncthreads();

    const int wave = tid >> 6;
    const int lane = tid & 63;
    const int tok_base = blockIdx.x * 16 + wave * 4;  // 16 tokens/block, never straddles a row

    double sacc = 0.0;
    for (int t = 0; t < 4; ++t) {
        const int tok = tok_base + t;
        const float* xp = x + (size_t)tok * DIM;
        double acc = 0.0;
        #pragma unroll
        for (int i = 0; i < DIM; i += 64 * 4) {
            float4 xv = *(const float4*)(xp + i + lane * 4);
            float4 wv = *(const float4*)(w_lds + i + lane * 4);
            acc += (double)xv.x * wv.x + (double)xv.y * wv.y
                 + (double)xv.z * wv.z + (double)xv.w * wv.w;
        }
        #pragma unroll
        for (int off = 32; off > 0; off >>= 1)
            acc += __shfl_down(acc, off, 64);
        if (lane == 0) {
            float logit = (float)acc;
            logits_out[tok] = logit;
            float noisy = logit + noise[tok] * 0.1f;
            unsigned u = __float_as_uint(noisy);
            keys_out[tok] = (u & 0x80000000u) ? ~u : (u | 0x80000000u);  // order-preserving
            sacc += (double)(1.0f / (1.0f + expf(-logit)));
        }
    }
    if (lane == 0) ssum[wave] = sacc;
    __syncthreads();
    if (tid == 0)
        block_sums[blockIdx.x] = ssum[0] + ssum[1] + ssum[2] + ssum[3];
}

// ---------------- Kernel 2: radix-4 register binary-search select ----------------
// One block (1024 threads, 16 waves) per row; 8 keys/thread in VGPRs.
// 16 rounds x (3 packed candidate counts in one 64-bit shuffle reduce).
__global__ __launch_bounds__(1024) void select_kernel(
    const unsigned* __restrict__ keys, float* __restrict__ mask_out)
{
    const int b = blockIdx.x;
    const int tid = threadIdx.x;
    const int wv = tid >> 6;
    __shared__ unsigned k_lds[SEQ];                 // for rare tie-rank fallback
    __shared__ unsigned long long wsum[2][16];

    unsigned kreg[8];
    const unsigned* kp = keys + b * SEQ;
    #pragma unroll
    for (int j = 0; j < 8; ++j) {
        unsigned v = kp[j * 1024 + tid];            // coalesced
        kreg[j] = v;
        k_lds[j * 1024 + tid] = v;
    }

    // thr ends as the CAP-th largest key: largest v with count(keys >= v) >= CAP
    unsigned thr = 0u;
    #pragma unroll 1
    for (int s = 30; s >= 0; s -= 2) {
        const unsigned c1 = thr | (1u << s);
        const unsigned c2 = thr | (2u << s);
        const unsigned c3 = thr | (3u << s);
        unsigned n1 = 0, n2 = 0, n3 = 0;
        #pragma unroll
        for (int j = 0; j < 8; ++j) {
            n1 += (kreg[j] >= c1);
            n2 += (kreg[j] >= c2);
            n3 += (kreg[j] >= c3);
        }
        unsigned long long p = (unsigned long long)n1
                             | ((unsigned long long)n2 << 21)
                             | ((unsigned long long)n3 << 42);
        #pragma unroll
        for (int off = 32; off > 0; off >>= 1) p += __shfl_xor(p, off, 64);
        if ((tid & 63) == 0) wsum[(s >> 1) & 1][wv] = p;
        __syncthreads();
        unsigned long long tot = 0;
        #pragma unroll
        for (int i = 0; i < 16; ++i) tot += wsum[(s >> 1) & 1][i];
        const unsigned t1 = (unsigned)(tot & 0x1FFFFFu);
        const unsigned t2 = (unsigned)((tot >> 21) & 0x1FFFFFu);
        const unsigned t3 = (unsigned)((tot >> 42) & 0x1FFFFFu);
        if      (t3 >= CAP) thr = c3;
        else if (t2 >= CAP) thr = c2;
        else if (t1 >= CAP) thr = c1;
    }

    // counts: strictly-greater and equal (packed), one more reduce
    {
        unsigned ng = 0, ne = 0;
        #pragma unroll
        for (int j = 0; j < 8; ++j) {
            ng += (kreg[j] > thr);
            ne += (kreg[j] == thr);
        }
        unsigned long long p = (unsigned long long)ng | ((unsigned long long)ne << 21);
        #pragma unroll
        for (int off = 32; off > 0; off >>= 1) p += __shfl_xor(p, off, 64);
        if ((tid & 63) == 0) wsum[1][wv] = p;   // last loop iter (s=0) used parity 0
        __syncthreads();
        unsigned long long tot = 0;
        #pragma unroll
        for (int i = 0; i < 16; ++i) tot += wsum[1][i];
        const int n_gt = (int)(tot & 0x1FFFFFu);
        const int n_eq = (int)((tot >> 21) & 0x1FFFFFu);
        const int kneed = CAP - n_gt;           // ties to take, lowest index first

        float* mp = mask_out + b * SEQ;
        if (n_eq == kneed) {
            // fast path (generic case incl. unique threshold): take all ties
            #pragma unroll
            for (int j = 0; j < 8; ++j)
                mp[j * 1024 + tid] = (kreg[j] >= thr) ? 1.0f : 0.0f;
        } else {
            // rare duplicate-key path: rank ties by index (matches lax.top_k)
            #pragma unroll
            for (int j = 0; j < 8; ++j) {
                const int i = j * 1024 + tid;
                const unsigned key = kreg[j];
                bool sel;
                if (key > thr) sel = true;
                else if (key == thr) {
                    int rank = 0;
                    for (int jj = 0; jj < i; ++jj) rank += (k_lds[jj] == thr);
                    sel = (rank < kneed);
                } else sel = false;
                mp[i] = sel ? 1.0f : 0.0f;
            }
        }
    }
}

// ---------------- Kernel 3: reduce block partials -> aux loss ----------------
__global__ __launch_bounds__(256) void finalize_kernel(
    const double* __restrict__ block_sums, float* __restrict__ aux_out)
{
    __shared__ double red[256];
    const int tid = threadIdx.x;
    const int per_row = GEMV_BLOCKS / BATCH;    // 512
    double aux = 0.0;
    for (int b = 0; b < BATCH; ++b) {
        double acc = 0.0;
        for (int i = tid; i < per_row; i += 256) acc += block_sums[b * per_row + i];
        red[tid] = acc;
        __syncthreads();
        for (int off = 128; off > 0; off >>= 1) {
            if (tid < off) red[tid] += red[tid + off];
            __syncthreads();
        }
        if (tid == 0) {
            double m = red[0] / (double)SEQ - 0.5;
            aux += m * m;
        }
        __syncthreads();
    }
    if (tid == 0) aux_out[0] = (float)(0.01 * (aux / (double)BATCH));
}

extern "C" void kernel_launch(void* const* d_in, const int* in_sizes, int n_in,
                              void* d_out, int out_size, void* d_ws, size_t ws_size,
                              hipStream_t stream) {
    const float* x     = (const float*)d_in[0];   // [B, L, D]
    const float* noise = (const float*)d_in[1];   // [B, L]
    const float* w     = (const float*)d_in[2];   // [D]

    float* mask_out   = (float*)d_out;                   // [B*L]
    float* logits_out = (float*)d_out + BATCH * SEQ;     // [B*L]
    float* aux_out    = (float*)d_out + 2 * BATCH * SEQ; // [1]

    unsigned* keys     = (unsigned*)d_ws;                                    // 128 KB
    double* block_sums = (double*)((char*)d_ws + (size_t)BATCH * SEQ * 4);   // 16 KB, 8B-aligned

    gemv_kernel<<<GEMV_BLOCKS, 256, 0, stream>>>(x, noise, w, logits_out, keys, block_sums);
    select_kernel<<<BATCH, 1024, 0, stream>>>(keys, mask_out);
    finalize_kernel<<<1, 256, 0, stream>>>(block_sums, aux_out);
}

// Round 4
// 375.486 us; speedup vs baseline: 1.8651x; 1.0123x over previous
//
#include <hip/hip_runtime.h>
#include <hip/hip_bf16.h>
#include <math.h>

// MoD router: B=4, L=8192, D=2048, capacity=4096
// out layout (float32): mask[B*L] ++ logits[B*L] ++ aux_loss[1]
// ws layout: keys[B*L] uint32 (128 KB) ++ block_sums[2048] double (16 KB)

#define BATCH 4
#define SEQ 8192
#define DIM 2048
#define CAP 4096
#define GEMV_BLOCKS ((BATCH * SEQ) / 16)   // 2048, 512 per row

// ---------------- Kernel 1: per-token GEMV + noisy keys + fused sigmoid partials ----
// block = 256 (4 waves), each wave computes 4 tokens; grid = 2048
__global__ __launch_bounds__(256) void gemv_kernel(
    const float* __restrict__ x, const float* __restrict__ noise,
    const float* __restrict__ w, float* __restrict__ logits_out,
    unsigned* __restrict__ keys_out, double* __restrict__ block_sums,
    float* __restrict__ aux_out)
{
    __shared__ float w_lds[DIM];
    __shared__ double ssum[4];
    const int tid = threadIdx.x;
    // zero the aux accumulator (d_out is poisoned 0xAA each iter); select's
    // atomics run in a later dispatch on the same stream -> ordering + visibility ok
    if (blockIdx.x == 0 && tid == 0) aux_out[0] = 0.0f;

    for (int i = tid * 4; i < DIM; i += 256 * 4) {
        *(float4*)(w_lds + i) = *(const float4*)(w + i);
    }
    __syncthreads();

    const int wave = tid >> 6;
    const int lane = tid & 63;
    const int tok_base = blockIdx.x * 16 + wave * 4;  // 16 tokens/block, never straddles a row

    double sacc = 0.0;
    for (int t = 0; t < 4; ++t) {
        const int tok = tok_base + t;
        const float* xp = x + (size_t)tok * DIM;
        double acc = 0.0;
        #pragma unroll
        for (int i = 0; i < DIM; i += 64 * 4) {
            float4 xv = *(const float4*)(xp + i + lane * 4);
            float4 wv = *(const float4*)(w_lds + i + lane * 4);
            acc += (double)xv.x * wv.x + (double)xv.y * wv.y
                 + (double)xv.z * wv.z + (double)xv.w * wv.w;
        }
        #pragma unroll
        for (int off = 32; off > 0; off >>= 1)
            acc += __shfl_down(acc, off, 64);
        if (lane == 0) {
            float logit = (float)acc;
            logits_out[tok] = logit;
            float noisy = logit + noise[tok] * 0.1f;
            unsigned u = __float_as_uint(noisy);
            keys_out[tok] = (u & 0x80000000u) ? ~u : (u | 0x80000000u);  // order-preserving
            sacc += (double)(1.0f / (1.0f + expf(-logit)));
        }
    }
    if (lane == 0) ssum[wave] = sacc;
    __syncthreads();
    if (tid == 0)
        block_sums[blockIdx.x] = ssum[0] + ssum[1] + ssum[2] + ssum[3];
}

// ---------------- Kernel 2: radix-4 register binary-search select + fused aux ----
// One block (1024 threads, 16 waves) per row; 8 keys/thread in VGPRs.
// 16 rounds x (3 packed candidate counts in one 64-bit shuffle reduce).
// Tail: reduce this row's 512 sigmoid partials and atomicAdd the aux term.
__global__ __launch_bounds__(1024) void select_kernel(
    const unsigned* __restrict__ keys, const double* __restrict__ block_sums,
    float* __restrict__ mask_out, float* __restrict__ aux_out)
{
    const int b = blockIdx.x;
    const int tid = threadIdx.x;
    const int wv = tid >> 6;
    __shared__ unsigned k_lds[SEQ];                 // for rare tie-rank fallback
    __shared__ unsigned long long wsum[2][16];
    __shared__ double dred[16];

    unsigned kreg[8];
    const unsigned* kp = keys + b * SEQ;
    #pragma unroll
    for (int j = 0; j < 8; ++j) {
        unsigned v = kp[j * 1024 + tid];            // coalesced
        kreg[j] = v;
        k_lds[j * 1024 + tid] = v;
    }

    // thr ends as the CAP-th largest key: largest v with count(keys >= v) >= CAP
    unsigned thr = 0u;
    #pragma unroll 1
    for (int s = 30; s >= 0; s -= 2) {
        const unsigned c1 = thr | (1u << s);
        const unsigned c2 = thr | (2u << s);
        const unsigned c3 = thr | (3u << s);
        unsigned n1 = 0, n2 = 0, n3 = 0;
        #pragma unroll
        for (int j = 0; j < 8; ++j) {
            n1 += (kreg[j] >= c1);
            n2 += (kreg[j] >= c2);
            n3 += (kreg[j] >= c3);
        }
        unsigned long long p = (unsigned long long)n1
                             | ((unsigned long long)n2 << 21)
                             | ((unsigned long long)n3 << 42);
        #pragma unroll
        for (int off = 32; off > 0; off >>= 1) p += __shfl_xor(p, off, 64);
        if ((tid & 63) == 0) wsum[(s >> 1) & 1][wv] = p;
        __syncthreads();
        unsigned long long tot = 0;
        #pragma unroll
        for (int i = 0; i < 16; ++i) tot += wsum[(s >> 1) & 1][i];
        const unsigned t1 = (unsigned)(tot & 0x1FFFFFu);
        const unsigned t2 = (unsigned)((tot >> 21) & 0x1FFFFFu);
        const unsigned t3 = (unsigned)((tot >> 42) & 0x1FFFFFu);
        if      (t3 >= CAP) thr = c3;
        else if (t2 >= CAP) thr = c2;
        else if (t1 >= CAP) thr = c1;
    }

    // counts: strictly-greater and equal (packed), one more reduce
    unsigned ng = 0, ne = 0;
    #pragma unroll
    for (int j = 0; j < 8; ++j) {
        ng += (kreg[j] > thr);
        ne += (kreg[j] == thr);
    }
    unsigned long long p = (unsigned long long)ng | ((unsigned long long)ne << 21);
    #pragma unroll
    for (int off = 32; off > 0; off >>= 1) p += __shfl_xor(p, off, 64);
    if ((tid & 63) == 0) wsum[1][wv] = p;   // last loop iter (s=0) used parity 0
    __syncthreads();
    unsigned long long tot = 0;
    #pragma unroll
    for (int i = 0; i < 16; ++i) tot += wsum[1][i];
    const int n_gt = (int)(tot & 0x1FFFFFu);
    const int n_eq = (int)((tot >> 21) & 0x1FFFFFu);
    const int kneed = CAP - n_gt;           // ties to take, lowest index first

    float* mp = mask_out + b * SEQ;
    if (n_eq == kneed) {
        // fast path (generic case incl. unique threshold): take all ties
        #pragma unroll
        for (int j = 0; j < 8; ++j)
            mp[j * 1024 + tid] = (kreg[j] >= thr) ? 1.0f : 0.0f;
    } else {
        // rare duplicate-key path: rank ties by index (matches lax.top_k)
        #pragma unroll
        for (int j = 0; j < 8; ++j) {
            const int i = j * 1024 + tid;
            const unsigned key = kreg[j];
            bool sel;
            if (key > thr) sel = true;
            else if (key == thr) {
                int rank = 0;
                for (int jj = 0; jj < i; ++jj) rank += (k_lds[jj] == thr);
                sel = (rank < kneed);
            } else sel = false;
            mp[i] = sel ? 1.0f : 0.0f;
        }
    }

    // fused aux-loss term for this row: sum 512 sigmoid partials, add 0.01*m^2/B
    const int per_row = GEMV_BLOCKS / BATCH;    // 512
    double acc = (tid < per_row) ? block_sums[b * per_row + tid] : 0.0;
    #pragma unroll
    for (int off = 32; off > 0; off >>= 1) acc += __shfl_xor(acc, off, 64);
    if ((tid & 63) == 0) dred[wv] = acc;
    __syncthreads();
    if (tid == 0) {
        double s = 0.0;
        #pragma unroll
        for (int i = 0; i < 16; ++i) s += dred[i];
        double m = s / (double)SEQ - 0.5;
        atomicAdd(aux_out, (float)(0.01 * (m * m) / (double)BATCH));
    }
}

extern "C" void kernel_launch(void* const* d_in, const int* in_sizes, int n_in,
                              void* d_out, int out_size, void* d_ws, size_t ws_size,
                              hipStream_t stream) {
    const float* x     = (const float*)d_in[0];   // [B, L, D]
    const float* noise = (const float*)d_in[1];   // [B, L]
    const float* w     = (const float*)d_in[2];   // [D]

    float* mask_out   = (float*)d_out;                   // [B*L]
    float* logits_out = (float*)d_out + BATCH * SEQ;     // [B*L]
    float* aux_out    = (float*)d_out + 2 * BATCH * SEQ; // [1]

    unsigned* keys     = (unsigned*)d_ws;                                    // 128 KB
    double* block_sums = (double*)((char*)d_ws + (size_t)BATCH * SEQ * 4);   // 16 KB, 8B-aligned

    gemv_kernel<<<GEMV_BLOCKS, 256, 0, stream>>>(x, noise, w, logits_out, keys,
                                                 block_sums, aux_out);
    select_kernel<<<BATCH, 1024, 0, stream>>>(keys, block_sums, mask_out, aux_out);
}